// Round 1
// baseline (411.895 us; speedup 1.0000x reference)
//
#include <hip/hip_runtime.h>

#define B_TOTAL 8192
#define T_FULL  100
#define XD      256
#define T0      30
#define TW      70      // time window length (30:100)
#define KS      50      // conv kernel size
#define NT      21      // TW - KS + 1 output positions
#define YOUT    300     // Y_DIM * 50
#define NB      8       // batches per block (fc_w L2-traffic amortization)

__global__ __launch_bounds__(256, 2)
void tiancnn_fused(const float* __restrict__ seq,
                   const float* __restrict__ conv_w,
                   const float* __restrict__ fc_w,
                   float* __restrict__ out) {
    __shared__ float feat[NB][XD];

    const int f  = threadIdx.x;          // feature index 0..255
    const int b0 = blockIdx.x * NB;

    // Per-feature depthwise conv weights -> registers (one-time, L2-cached)
    float w[KS];
#pragma unroll
    for (int k = 0; k < KS; ++k) w[k] = conv_w[f * KS + k];

    // ---- Conv + ReLU + time-max for NB batches ----
    for (int nb = 0; nb < NB; ++nb) {
        const int b = b0 + nb;
        const float* xp = seq + ((size_t)b * T_FULL + T0) * XD + f;

        // Coalesced column read: lanes f..f+63 hit 256 contiguous bytes/row
        float xv[TW];
#pragma unroll
        for (int t = 0; t < TW; ++t) xv[t] = xp[(size_t)t * XD];

        float m = 0.f;   // max(relu(y)) == max(0, max_t y[t])
#pragma unroll
        for (int t = 0; t < NT; ++t) {
            float acc = 0.f;
#pragma unroll
            for (int k = 0; k < KS; ++k) acc = fmaf(xv[t + k], w[k], acc);
            m = fmaxf(m, acc);
        }
        feat[nb][f] = m;
    }
    __syncthreads();

    // ---- FC: out[b0+nb][o] = dot(feat[nb], fc_w[o]) ----
    for (int idx = threadIdx.x; idx < NB * YOUT; idx += 256) {
        const int nb = idx / YOUT;
        const int o  = idx - nb * YOUT;
        const float4* wrow = reinterpret_cast<const float4*>(fc_w + (size_t)o * XD);
        const float*  fv   = feat[nb];
        float acc = 0.f;
#pragma unroll
        for (int q = 0; q < XD / 4; ++q) {
            const float4 wv = wrow[q];
            acc = fmaf(wv.x, fv[4 * q + 0], acc);
            acc = fmaf(wv.y, fv[4 * q + 1], acc);
            acc = fmaf(wv.z, fv[4 * q + 2], acc);
            acc = fmaf(wv.w, fv[4 * q + 3], acc);
        }
        out[(size_t)(b0 + nb) * YOUT + o] = acc;
    }
}

extern "C" void kernel_launch(void* const* d_in, const int* in_sizes, int n_in,
                              void* d_out, int out_size, void* d_ws, size_t ws_size,
                              hipStream_t stream) {
    const float* seq    = (const float*)d_in[0];
    const float* conv_w = (const float*)d_in[1];
    const float* fc_w   = (const float*)d_in[2];
    float*       out    = (float*)d_out;

    tiancnn_fused<<<dim3(B_TOTAL / NB), dim3(256), 0, stream>>>(seq, conv_w, fc_w, out);
}